// Round 1
// baseline (44.677 us; speedup 1.0000x reference)
//
#include <hip/hip_runtime.h>
#include <math.h>

// YOLO-v1 style loss, S=7, B=2, C=20. One thread per grid cell.
constexpr int NCH = 30;        // channels per cell (B*5 + C)
constexpr int CLS = 20;
constexpr int CPB = 256;       // cells per block
constexpr int NTHREADS = 256;

__global__ __launch_bounds__(NTHREADS) void yolo_loss_main(
    const float* __restrict__ pred, const float* __restrict__ targ,
    float* __restrict__ partial, int ncells)
{
  __shared__ float sp[CPB * NCH];          // 30720 B
  __shared__ float st[CPB * NCH];          // 30720 B
  __shared__ float swred[NTHREADS / 64];

  const int tid = threadIdx.x;
  const int cell0 = blockIdx.x * CPB;
  const int nc = min(CPB, ncells - cell0);
  const size_t base = (size_t)cell0 * NCH;

  // ---- stage global -> LDS, coalesced ----
  if (nc == CPB) {
    const float4* gp = (const float4*)(pred + base);
    const float4* gt = (const float4*)(targ + base);
    float4* lp = (float4*)sp;
    float4* lt = (float4*)st;
    for (int i = tid; i < CPB * NCH / 4; i += NTHREADS) {
      lp[i] = gp[i];
      lt[i] = gt[i];
    }
  } else {  // tail block (not hit for NB=16384, kept for safety)
    int nfl = nc * NCH;
    for (int i = tid; i < nfl; i += NTHREADS) {
      sp[i] = pred[base + i];
      st[i] = targ[base + i];
    }
  }
  __syncthreads();

  float sum = 0.0f;
  if (tid < nc) {
    const float* p = sp + tid * NCH;
    const float* t = st + tid * NCH;
    int cellg = cell0 + tid;
    int rem = cellg % 49;
    int row = rem / 7;
    float fi = (float)row;            // y offset (grid[i][j] = (j, i))
    float fj = (float)(rem - row * 7);// x offset

    float tx = t[0], ty = t[1], tw = t[2], th = t[3], tobj = t[4];
    float gx = (tx + fj) / 7.0f;
    float gy = (ty + fi) / 7.0f;
    float g1x = gx - 0.5f * tw, g1y = gy - 0.5f * th;
    float g2x = gx + 0.5f * tw, g2y = gy + 0.5f * th;
    float area_g = tw * th;

    float px0 = p[0], py0 = p[1], pw0 = p[2], ph0 = p[3], pc0 = p[4];
    float px1 = p[5], py1 = p[6], pw1 = p[7], ph1 = p[8], pc1 = p[9];

    float iou0, iou1;
    {
      float cx = (px0 + fj) / 7.0f, cy = (py0 + fi) / 7.0f;
      float wx = fminf(g2x, cx + 0.5f * pw0) - fmaxf(g1x, cx - 0.5f * pw0);
      float wy = fminf(g2y, cy + 0.5f * ph0) - fmaxf(g1y, cy - 0.5f * ph0);
      wx = fmaxf(wx, 0.0f); wy = fmaxf(wy, 0.0f);
      float inter = wx * wy;
      iou0 = inter / (area_g + pw0 * ph0 - inter);
    }
    {
      float cx = (px1 + fj) / 7.0f, cy = (py1 + fi) / 7.0f;
      float wx = fminf(g2x, cx + 0.5f * pw1) - fmaxf(g1x, cx - 0.5f * pw1);
      float wy = fminf(g2y, cy + 0.5f * ph1) - fmaxf(g1y, cy - 0.5f * ph1);
      wx = fmaxf(wx, 0.0f); wy = fmaxf(wy, 0.0f);
      float inter = wx * wy;
      iou1 = inter / (area_g + pw1 * ph1 - inter);
    }

    bool b1 = (iou1 > iou0);              // argmax: ties -> box 0
    float biou = fmaxf(iou0, iou1);
    bool obj = (tobj == 1.0f);            // tobj is exactly 0.0 or 1.0

    // negative-confidence loss: neg_w[b] = obj ? (b != best) : 1
    float lneg = 0.0f;
    if (!obj || b1)  lneg += pc0 * pc0;
    if (!obj || !b1) lneg += pc1 * pc1;
    sum = 0.5f * lneg;

    if (obj) {
      float bx = b1 ? px1 : px0;
      float by = b1 ? py1 : py0;
      float bw = b1 ? pw1 : pw0;
      float bh = b1 ? ph1 : ph0;
      float bc = b1 ? pc1 : pc0;
      float dx = bx - tx, dy = by - ty;
      sum += 5.0f * (dx * dx + dy * dy);
      float cw = fminf(fmaxf(bw, 0.0f), 1.0f);
      float chh = fminf(fmaxf(bh, 0.0f), 1.0f);
      float sw_ = sqrtf(cw) - sqrtf(tw);
      float sh_ = sqrtf(chh) - sqrtf(th);
      sum += 5.0f * (sw_ * sw_ + sh_ * sh_);
      float dc = bc - biou;
      sum += dc * dc;
      float lcls = 0.0f;
      #pragma unroll
      for (int k = 0; k < CLS; ++k) {
        float d = p[10 + k] - t[10 + k];
        lcls += d * d;
      }
      sum += lcls;
    }
  }

  // ---- block reduction ----
  #pragma unroll
  for (int off = 32; off > 0; off >>= 1) sum += __shfl_down(sum, off);
  if ((tid & 63) == 0) swred[tid >> 6] = sum;
  __syncthreads();
  if (tid == 0) {
    float s = 0.0f;
    #pragma unroll
    for (int w = 0; w < NTHREADS / 64; ++w) s += swred[w];
    partial[blockIdx.x] = s;
  }
}

__global__ __launch_bounds__(256) void yolo_loss_reduce(
    const float* __restrict__ partial, int n, float* __restrict__ out,
    float scale)
{
  __shared__ float swred[4];
  float s = 0.0f;
  for (int i = threadIdx.x; i < n; i += 256) s += partial[i];
  #pragma unroll
  for (int off = 32; off > 0; off >>= 1) s += __shfl_down(s, off);
  if ((threadIdx.x & 63) == 0) swred[threadIdx.x >> 6] = s;
  __syncthreads();
  if (threadIdx.x == 0)
    out[0] = (swred[0] + swred[1] + swred[2] + swred[3]) * scale;
}

extern "C" void kernel_launch(void* const* d_in, const int* in_sizes, int n_in,
                              void* d_out, int out_size, void* d_ws, size_t ws_size,
                              hipStream_t stream) {
  const float* pred = (const float*)d_in[0];
  const float* targ = (const float*)d_in[1];
  float* out = (float*)d_out;
  float* partial = (float*)d_ws;

  int total = in_sizes[0];              // nb*49*30
  int ncells = total / NCH;
  int nb = ncells / 49;
  int blocks = (ncells + CPB - 1) / CPB;
  float scale = 1.0f / ((float)nb * (float)nb);

  yolo_loss_main<<<blocks, NTHREADS, 0, stream>>>(pred, targ, partial, ncells);
  yolo_loss_reduce<<<1, 256, 0, stream>>>(partial, blocks, out, scale);
}